// Round 4
// baseline (371.353 us; speedup 1.0000x reference)
//
#include <hip/hip_runtime.h>
#include <math.h>

constexpr int Bn = 1024, DH = 2048, K1 = 4096, DO = 1024, NL = 128;
constexpr int MN = Bn * DO;   // 1M elements
constexpr int SPS = Bn * NL;  // 128K floats per score slice

typedef __bf16 bf16x8 __attribute__((ext_vector_type(8)));
typedef short  s16x8  __attribute__((ext_vector_type(8)));
typedef float  f32x4  __attribute__((ext_vector_type(4)));

__device__ __forceinline__ unsigned short f2bf(float f) {
  union { float f; unsigned u; } v; v.f = f;
  unsigned r = v.u + 0x7FFFu + ((v.u >> 16) & 1u);  // RNE
  return (unsigned short)(r >> 16);
}
__device__ __forceinline__ float bf2f(unsigned h) {
  union { unsigned u; float f; } v; v.u = h << 16; return v.f;
}

// ---------- prep: concat+relu+bf16 (blocks 0..2047) + W1/W2 transposes
// + zero the score completion counters (block 2048, lanes 0..31). ----------
__global__ __launch_bounds__(256)
void prep(const float* __restrict__ sbj, const float* __restrict__ obj,
          const float* __restrict__ W1, const float* __restrict__ W2,
          unsigned short* __restrict__ Abf,
          unsigned short* __restrict__ W1t, unsigned short* __restrict__ W2t,
          int* __restrict__ cnt) {
  const int tid = threadIdx.x;
  if (blockIdx.x < 2048) {
    const int t = blockIdx.x * 256 + tid;
    const int m = t >> 9;
    const int k = (t & 511) << 3;
    const float* src = (k < DH) ? sbj + (size_t)m * DH + k
                                : obj + (size_t)m * DH + (k - DH);
    const float4 a = ((const float4*)src)[0];
    const float4 b = ((const float4*)src)[1];
    uint4 o;
    o.x = (unsigned)f2bf(fmaxf(a.x, 0.f)) | ((unsigned)f2bf(fmaxf(a.y, 0.f)) << 16);
    o.y = (unsigned)f2bf(fmaxf(a.z, 0.f)) | ((unsigned)f2bf(fmaxf(a.w, 0.f)) << 16);
    o.z = (unsigned)f2bf(fmaxf(b.x, 0.f)) | ((unsigned)f2bf(fmaxf(b.y, 0.f)) << 16);
    o.w = (unsigned)f2bf(fmaxf(b.z, 0.f)) | ((unsigned)f2bf(fmaxf(b.w, 0.f)) << 16);
    *(uint4*)&Abf[(size_t)m * K1 + k] = o;
    return;
  }
  __shared__ float tl[64][65];
  const int tb = blockIdx.x - 2048;
  if (tb == 0 && tid < 32) cnt[tid] = 0;  // visible to later dispatches via stream ordering
  int by = tb >> 4;
  const int c0 = (tb & 15) * 64;
  const float* in; unsigned short* out; int R;
  if (by < 64) { in = W1; out = W1t; R = K1; }
  else         { in = W2; out = W2t; R = DO; by -= 64; }
  const int r0 = by * 64;
  {
    const int rr = tid >> 4, cc = (tid & 15) * 4;
    #pragma unroll
    for (int i = 0; i < 4; ++i) {
      const float4 v = *(const float4*)&in[(size_t)(r0 + rr + i * 16) * DO + c0 + cc];
      tl[rr + i * 16][cc + 0] = v.x; tl[rr + i * 16][cc + 1] = v.y;
      tl[rr + i * 16][cc + 2] = v.z; tl[rr + i * 16][cc + 3] = v.w;
    }
  }
  __syncthreads();
  {
    const int r4 = (tid & 15) * 4;
    #pragma unroll
    for (int i = 0; i < 4; ++i) {
      const int cr = i * 16 + (tid >> 4);
      uint2 o;
      o.x = (unsigned)f2bf(tl[r4 + 0][cr]) | ((unsigned)f2bf(tl[r4 + 1][cr]) << 16);
      o.y = (unsigned)f2bf(tl[r4 + 2][cr]) | ((unsigned)f2bf(tl[r4 + 3][cr]) << 16);
      *(uint2*)&out[(size_t)(c0 + cr) * R + r0 + r4] = o;
    }
  }
}

// ---------- GEMM1: 128x128 tile, 4 waves in 2x2 (64x64 quadrant each),
// BK=64, split-K=8 with z = XCD (bid&7). global_load_lds both operands,
// double-buffered LDS, one barrier per iter. bf16 partials P[z]. ----------
template <int KSLICE>
__global__ __launch_bounds__(256, 2)
void mfma_gemm(const unsigned short* __restrict__ A,
               const unsigned short* __restrict__ Bt,
               unsigned short* __restrict__ P, int K) {
  __shared__ __align__(16) unsigned short smem[2][2 * 128 * 64];  // 2 x 32 KB

  const int tid = threadIdx.x;
  const int w = tid >> 6, l = tid & 63;
  const int bid = blockIdx.x;
  const int z = bid & 7, t = bid >> 3;
  const int m0 = (t >> 3) * 128, n0 = (t & 7) * 128;
  const int kb = z * KSLICE;

  f32x4 acc[4][4] = {};

  constexpr int NIT = KSLICE / 64;

  auto stage = [&](int buf, int it) {
    const int k0 = kb + it * 64;
    unsigned short* LA = smem[buf];
    unsigned short* LB = smem[buf] + 128 * 64;
    #pragma unroll
    for (int i = 0; i < 4; ++i) {
      const int c = i * 256 + tid, row = c >> 3, kc = c & 7;
      const int kcg = kc ^ (row & 7);
      __builtin_amdgcn_global_load_lds(
          (const __attribute__((address_space(1))) unsigned int*)(A + (size_t)(m0 + row) * K + k0 + kcg * 8),
          (__attribute__((address_space(3))) unsigned int*)&LA[c * 8], 16, 0, 0);
    }
    #pragma unroll
    for (int i = 0; i < 4; ++i) {
      const int c = i * 256 + tid, row = c >> 3, kc = c & 7;
      const int kcg = kc ^ (row & 7);
      __builtin_amdgcn_global_load_lds(
          (const __attribute__((address_space(1))) unsigned int*)(Bt + (size_t)(n0 + row) * K + k0 + kcg * 8),
          (__attribute__((address_space(3))) unsigned int*)&LB[c * 8], 16, 0, 0);
    }
  };

  stage(0, 0);
  int cur = 0;
  for (int it = 0; it < NIT; ++it) {
    __syncthreads();                 // drains vmcnt: buf[cur] ready; prior readers done
    if (it + 1 < NIT) stage(cur ^ 1, it + 1);   // async prefetch next tile

    const unsigned short* LA = smem[cur];
    const unsigned short* LB = smem[cur] + 128 * 64;
    #pragma unroll
    for (int s = 0; s < 2; ++s) {
      const int kcq = s * 4 + (l >> 4);
      bf16x8 af[4], bfr[4];
      #pragma unroll
      for (int i = 0; i < 4; ++i) {
        const int r = (w >> 1) * 64 + i * 16 + (l & 15);
        const int kca = kcq ^ (r & 7);
        af[i] = __builtin_bit_cast(bf16x8, *(const s16x8*)&LA[(r * 8 + kca) * 8]);
      }
      #pragma unroll
      for (int j = 0; j < 4; ++j) {
        const int rr = (w & 1) * 64 + j * 16 + (l & 15);
        const int kcb = kcq ^ (rr & 7);
        bfr[j] = __builtin_bit_cast(bf16x8, *(const s16x8*)&LB[(rr * 8 + kcb) * 8]);
      }
      #pragma unroll
      for (int i = 0; i < 4; ++i)
        #pragma unroll
        for (int j = 0; j < 4; ++j)
          acc[i][j] = __builtin_amdgcn_mfma_f32_16x16x32_bf16(af[i], bfr[j], acc[i][j], 0, 0, 0);
    }
    cur ^= 1;
  }

  unsigned short* Pz = P + (size_t)z * MN;
  #pragma unroll
  for (int i = 0; i < 4; ++i) {
    #pragma unroll
    for (int r = 0; r < 4; ++r) {
      const int m = m0 + (w >> 1) * 64 + i * 16 + (l >> 4) * 4 + r;
      #pragma unroll
      for (int j = 0; j < 4; ++j) {
        const int n = n0 + (w & 1) * 64 + j * 16 + (l & 15);
        Pz[(size_t)m * DO + n] = f2bf(acc[i][j][r]);
      }
    }
  }
}

// ---------- combine1: H = relu(sum_z bf16 P[z] + b1) -> bf16 (uint4 loads) ----------
__global__ __launch_bounds__(256)
void combine1(const unsigned short* __restrict__ P, const float* __restrict__ bias,
              unsigned short* __restrict__ out) {
  const int t = threadIdx.x;
  const int row = blockIdx.x * 2 + (t >> 7);
  const int col = (t & 127) * 8;
  const size_t base = (size_t)row * DO + col;
  float s[8] = {};
  #pragma unroll
  for (int c = 0; c < 8; ++c) {
    const uint4 wv = *(const uint4*)&P[(size_t)c * MN + base];
    s[0] += bf2f(wv.x & 0xFFFFu); s[1] += bf2f(wv.x >> 16);
    s[2] += bf2f(wv.y & 0xFFFFu); s[3] += bf2f(wv.y >> 16);
    s[4] += bf2f(wv.z & 0xFFFFu); s[5] += bf2f(wv.z >> 16);
    s[6] += bf2f(wv.w & 0xFFFFu); s[7] += bf2f(wv.w >> 16);
  }
  const f32x4 b0 = *(const f32x4*)&bias[col];
  const f32x4 b1v = *(const f32x4*)&bias[col + 4];
  #pragma unroll
  for (int i = 0; i < 4; ++i) s[i] = fmaxf(s[i] + b0[i], 0.f);
  #pragma unroll
  for (int i = 0; i < 4; ++i) s[4 + i] = fmaxf(s[4 + i] + b1v[i], 0.f);
  uint4 o;
  o.x = (unsigned)f2bf(s[0]) | ((unsigned)f2bf(s[1]) << 16);
  o.y = (unsigned)f2bf(s[2]) | ((unsigned)f2bf(s[3]) << 16);
  o.z = (unsigned)f2bf(s[4]) | ((unsigned)f2bf(s[5]) << 16);
  o.w = (unsigned)f2bf(s[6]) | ((unsigned)f2bf(s[7]) << 16);
  *(uint4*)&out[base] = o;
}

// ---------- GEMM2 (full-K): 64x64 tile, in-block 4-wave k-split, BK=128,
// double-buffered LDS 2-phase pipeline, LDS tree-reduce,
// epilogue writes E = sum + b2 directly (fp32). ----------
__global__ __launch_bounds__(256, 2)
void gemm2_full(const unsigned short* __restrict__ A,
                const unsigned short* __restrict__ Bt,
                const float* __restrict__ b2, float* __restrict__ E) {
  __shared__ __align__(16) unsigned short smem[2][2 * 64 * 128];  // 2 x 32 KB

  const int tid = threadIdx.x;
  const int w = tid >> 6, l = tid & 63;
  const int bid = blockIdx.x;
  const int m0 = (bid >> 4) * 64, n0 = (bid & 15) * 64;

  f32x4 acc[4][4] = {};

  auto stage = [&](int buf, int it) {
    const int k0 = it * 128;
    unsigned short* LA = smem[buf];
    unsigned short* LB = smem[buf] + 64 * 128;
    #pragma unroll
    for (int i = 0; i < 4; ++i) {
      const int c = i * 256 + tid, m = c >> 4, kc = c & 15;
      const int kcg = (kc & 8) | ((kc & 7) ^ (m & 7));
      __builtin_amdgcn_global_load_lds(
          (const __attribute__((address_space(1))) unsigned int*)(A + (size_t)(m0 + m) * DO + k0 + kcg * 8),
          (__attribute__((address_space(3))) unsigned int*)&LA[c * 8], 16, 0, 0);
    }
    #pragma unroll
    for (int i = 0; i < 4; ++i) {
      const int c = i * 256 + tid, n = c >> 4, kc = c & 15;
      const int kcg = (kc & 8) | ((kc & 7) ^ (n & 7));
      __builtin_amdgcn_global_load_lds(
          (const __attribute__((address_space(1))) unsigned int*)(Bt + (size_t)(n0 + n) * DO + k0 + kcg * 8),
          (__attribute__((address_space(3))) unsigned int*)&LB[c * 8], 16, 0, 0);
    }
  };

  stage(0, 0);
  int cur = 0;
  for (int it = 0; it < 8; ++it) {  // K=1024, BK=128
    __syncthreads();
    if (it + 1 < 8) stage(cur ^ 1, it + 1);

    const unsigned short* LA = smem[cur];
    const unsigned short* LB = smem[cur] + 64 * 128;
    const int kcq = w * 4 + (l >> 4);
    bf16x8 af[4], bfr[4];
    #pragma unroll
    for (int i = 0; i < 4; ++i) {
      const int r = i * 16 + (l & 15);
      const int kca = (kcq & 8) | ((kcq & 7) ^ (r & 7));
      af[i]  = __builtin_bit_cast(bf16x8, *(const s16x8*)&LA[(r * 16 + kca) * 8]);
      bfr[i] = __builtin_bit_cast(bf16x8, *(const s16x8*)&LB[(r * 16 + kca) * 8]);
    }
    #pragma unroll
    for (int i = 0; i < 4; ++i)
      #pragma unroll
      for (int j = 0; j < 4; ++j)
        acc[i][j] = __builtin_amdgcn_mfma_f32_16x16x32_bf16(af[i], bfr[j], acc[i][j], 0, 0, 0);
    cur ^= 1;
  }
  __syncthreads();

  float* red = (float*)smem;
  if (w >= 2) {
    #pragma unroll
    for (int i = 0; i < 4; ++i)
      #pragma unroll
      for (int j = 0; j < 4; ++j)
        *(f32x4*)&red[(w - 2) * 4096 + ((i * 4 + j) * 64 + l) * 4] = acc[i][j];
  }
  __syncthreads();
  if (w < 2) {
    #pragma unroll
    for (int i = 0; i < 4; ++i)
      #pragma unroll
      for (int j = 0; j < 4; ++j)
        acc[i][j] += *(const f32x4*)&red[w * 4096 + ((i * 4 + j) * 64 + l) * 4];
  }
  __syncthreads();
  if (w == 1) {
    #pragma unroll
    for (int i = 0; i < 2; ++i)
      #pragma unroll
      for (int j = 0; j < 4; ++j)
        *(f32x4*)&red[((i * 4 + j) * 64 + l) * 4] = acc[i][j];
  } else if (w == 0) {
    #pragma unroll
    for (int i = 0; i < 2; ++i)
      #pragma unroll
      for (int j = 0; j < 4; ++j)
        *(f32x4*)&red[2048 + ((i * 4 + j) * 64 + l) * 4] = acc[i + 2][j];
  }
  __syncthreads();
  if (w >= 2) return;

  if (w == 0) {
    #pragma unroll
    for (int i = 0; i < 2; ++i) {
      #pragma unroll
      for (int j = 0; j < 4; ++j)
        acc[i][j] += *(const f32x4*)&red[((i * 4 + j) * 64 + l) * 4];
      #pragma unroll
      for (int r = 0; r < 4; ++r) {
        const int m = m0 + i * 16 + (l >> 4) * 4 + r;
        #pragma unroll
        for (int j = 0; j < 4; ++j) {
          const int n = n0 + j * 16 + (l & 15);
          E[(size_t)m * DO + n] = acc[i][j][r] + b2[n];
        }
      }
    }
  } else {
    #pragma unroll
    for (int i = 0; i < 2; ++i) {
      #pragma unroll
      for (int j = 0; j < 4; ++j)
        acc[i + 2][j] += *(const f32x4*)&red[2048 + ((i * 4 + j) * 64 + l) * 4];
      #pragma unroll
      for (int r = 0; r < 4; ++r) {
        const int m = m0 + (i + 2) * 16 + (l >> 4) * 4 + r;
        #pragma unroll
        for (int j = 0; j < 4; ++j) {
          const int n = n0 + j * 16 + (l & 15);
          E[(size_t)m * DO + n] = acc[i + 2][j][r] + b2[n];
        }
      }
    }
  }
}

// ---------- scores: d-split partials (8 slices, 2 chunks of 64 each);
// fused finalize: SP slices stored device-coherent; the 8th block per
// b-chunk (completion counter) re-reads all slices and writes -sqrt(sum). ----------
__global__ __launch_bounds__(256)
void score_partial(const float* __restrict__ E, const float* __restrict__ labels,
                   float* __restrict__ SP, int* __restrict__ cnt,
                   float* __restrict__ out) {
  __shared__ float es[64][33];   // [d][b]
  __shared__ float ls[64][132];  // [d][l]
  __shared__ int last;
  const int tid = threadIdx.x;
  const int b0 = blockIdx.x * 32;

  const int tb = tid & 15;   // b-pair
  const int tl = tid >> 4;   // label-octet
  float acc[2][8] = {};

  #pragma unroll
  for (int ch = 0; ch < 2; ++ch) {
    const int d0 = blockIdx.y * 128 + ch * 64;
    if (ch) __syncthreads();   // previous chunk's readers done before overwrite

    #pragma unroll
    for (int i = 0; i < 2; ++i) {
      const int fi = tid + i * 256;
      const int b = fi >> 4, dq = fi & 15;
      const float4 v = *(const float4*)&E[(size_t)(b0 + b) * DO + d0 + dq * 4];
      es[dq * 4 + 0][b] = v.x; es[dq * 4 + 1][b] = v.y;
      es[dq * 4 + 2][b] = v.z; es[dq * 4 + 3][b] = v.w;
    }
    #pragma unroll
    for (int i = 0; i < 8; ++i) {
      const int fi = tid + i * 256;
      const int lr = fi >> 4, dq = fi & 15;
      const float4 v = *(const float4*)&labels[(size_t)lr * DO + d0 + dq * 4];
      ls[dq * 4 + 0][lr] = v.x; ls[dq * 4 + 1][lr] = v.y;
      ls[dq * 4 + 2][lr] = v.z; ls[dq * 4 + 3][lr] = v.w;
    }
    __syncthreads();

    for (int dd = 0; dd < 64; ++dd) {
      const float e0 = es[dd][tb * 2 + 0];
      const float e1 = es[dd][tb * 2 + 1];
      const float4 l0 = *(const float4*)&ls[dd][tl * 8];
      const float4 l1 = *(const float4*)&ls[dd][tl * 8 + 4];
      const float lv[8] = {l0.x, l0.y, l0.z, l0.w, l1.x, l1.y, l1.z, l1.w};
      #pragma unroll
      for (int j = 0; j < 8; ++j) {
        float t0 = fmaxf(lv[j] - e0, 0.f); acc[0][j] = fmaf(t0, t0, acc[0][j]);
        float t1 = fmaxf(lv[j] - e1, 0.f); acc[1][j] = fmaf(t1, t1, acc[1][j]);
      }
    }
  }

  // store this slice's partials device-coherent (visible cross-XCD)
  float* SPz = SP + (size_t)blockIdx.y * SPS;
  #pragma unroll
  for (int i = 0; i < 2; ++i) {
    const size_t base = (size_t)(b0 + tb * 2 + i) * NL + tl * 8;
    #pragma unroll
    for (int j = 0; j < 8; ++j)
      __hip_atomic_store(&SPz[base + j], acc[i][j],
                         __ATOMIC_RELEASE, __HIP_MEMORY_SCOPE_AGENT);
  }
  __syncthreads();
  if (tid == 0)
    last = __hip_atomic_fetch_add(&cnt[blockIdx.x], 1,
                                  __ATOMIC_ACQ_REL, __HIP_MEMORY_SCOPE_AGENT);
  __syncthreads();
  if (last != 7) return;

  // finalize this b-chunk: 32 b x 128 l = 4096 scores, 16 per thread
  #pragma unroll
  for (int q = 0; q < 16; ++q) {
    const int idx = tid * 16 + q;
    const int b = idx >> 7, l = idx & 127;
    const size_t off = (size_t)(b0 + b) * NL + l;
    float s = 0.f;
    #pragma unroll
    for (int c = 0; c < 8; ++c)
      s += __hip_atomic_load(&SP[(size_t)c * SPS + off],
                             __ATOMIC_ACQUIRE, __HIP_MEMORY_SCOPE_AGENT);
    out[off] = -sqrtf(s);
  }
}

extern "C" void kernel_launch(void* const* d_in, const int* in_sizes, int n_in,
                              void* d_out, int out_size, void* d_ws, size_t ws_size,
                              hipStream_t stream) {
  const float* sbj  = (const float*)d_in[0];
  const float* obj  = (const float*)d_in[1];
  const float* W1   = (const float*)d_in[2];
  const float* b1   = (const float*)d_in[3];
  const float* W2   = (const float*)d_in[4];
  const float* b2   = (const float*)d_in[5];
  const float* labs = (const float*)d_in[6];
  float* scores = (float*)d_out;
  char* ws = (char*)d_ws;

  // Layout (MB): Abf [0,8)  W1t [8,16)  W2t [16,18)  H [18,20)  E [20,24)
  //              P [24,40) = 8 x 2 MB bf16    SP [40,44)    cnt [44,..)
  unsigned short* Abf = (unsigned short*)(ws);
  unsigned short* W1t = (unsigned short*)(ws + (8ull << 20));
  unsigned short* W2t = (unsigned short*)(ws + (16ull << 20));
  unsigned short* H   = (unsigned short*)(ws + (18ull << 20));
  float* E  = (float*)(ws + (20ull << 20));
  unsigned short* P = (unsigned short*)(ws + (24ull << 20));
  float* SP = (float*)(ws + (40ull << 20));
  int*   cnt = (int*)(ws + (44ull << 20));

  dim3 blk(256);
  prep<<<dim3(2048 + 1280), blk, 0, stream>>>(sbj, obj, W1, W2, Abf, W1t, W2t, cnt);

  // GEMM1: K=4096, 128^2 tiles, split-K=8 (KSLICE=512), z = XCD, bf16 partials
  mfma_gemm<512><<<dim3(512), blk, 0, stream>>>(Abf, W1t, P, K1);
  combine1<<<dim3(512), blk, 0, stream>>>(P, b1, H);
  // GEMM2: full-K, direct E output (no partials)
  gemm2_full<<<dim3(256), blk, 0, stream>>>(H, W2t, b2, E);
  // scores: 8 d-slices (2 chunks of 64 per block), fused finalize via counter
  score_partial<<<dim3(32, 8), blk, 0, stream>>>(E, labs, SP, cnt, scores);
}

// Round 5
// 134.610 us; speedup vs baseline: 2.7587x; 2.7587x over previous
//
#include <hip/hip_runtime.h>
#include <math.h>

constexpr int Bn = 1024, DH = 2048, K1 = 4096, DO = 1024, NL = 128;
constexpr int MN = Bn * DO;  // 1M elements

typedef __bf16 bf16x8 __attribute__((ext_vector_type(8)));
typedef short  s16x8  __attribute__((ext_vector_type(8)));
typedef float  f32x4  __attribute__((ext_vector_type(4)));

__device__ __forceinline__ unsigned short f2bf(float f) {
  union { float f; unsigned u; } v; v.f = f;
  unsigned r = v.u + 0x7FFFu + ((v.u >> 16) & 1u);  // RNE
  return (unsigned short)(r >> 16);
}
__device__ __forceinline__ float bf2f(unsigned h) {
  union { unsigned u; float f; } v; v.u = h << 16; return v.f;
}

// ---------- prep: concat+relu+bf16 (blocks 0..2047) + W1/W2 transposes ----------
__global__ __launch_bounds__(256)
void prep(const float* __restrict__ sbj, const float* __restrict__ obj,
          const float* __restrict__ W1, const float* __restrict__ W2,
          unsigned short* __restrict__ Abf,
          unsigned short* __restrict__ W1t, unsigned short* __restrict__ W2t) {
  const int tid = threadIdx.x;
  if (blockIdx.x < 2048) {
    const int t = blockIdx.x * 256 + tid;
    const int m = t >> 9;
    const int k = (t & 511) << 3;
    const float* src = (k < DH) ? sbj + (size_t)m * DH + k
                                : obj + (size_t)m * DH + (k - DH);
    const float4 a = ((const float4*)src)[0];
    const float4 b = ((const float4*)src)[1];
    uint4 o;
    o.x = (unsigned)f2bf(fmaxf(a.x, 0.f)) | ((unsigned)f2bf(fmaxf(a.y, 0.f)) << 16);
    o.y = (unsigned)f2bf(fmaxf(a.z, 0.f)) | ((unsigned)f2bf(fmaxf(a.w, 0.f)) << 16);
    o.z = (unsigned)f2bf(fmaxf(b.x, 0.f)) | ((unsigned)f2bf(fmaxf(b.y, 0.f)) << 16);
    o.w = (unsigned)f2bf(fmaxf(b.z, 0.f)) | ((unsigned)f2bf(fmaxf(b.w, 0.f)) << 16);
    *(uint4*)&Abf[(size_t)m * K1 + k] = o;
    return;
  }
  __shared__ float tl[64][65];
  const int tb = blockIdx.x - 2048;
  int by = tb >> 4;
  const int c0 = (tb & 15) * 64;
  const float* in; unsigned short* out; int R;
  if (by < 64) { in = W1; out = W1t; R = K1; }
  else         { in = W2; out = W2t; R = DO; by -= 64; }
  const int r0 = by * 64;
  {
    const int rr = tid >> 4, cc = (tid & 15) * 4;
    #pragma unroll
    for (int i = 0; i < 4; ++i) {
      const float4 v = *(const float4*)&in[(size_t)(r0 + rr + i * 16) * DO + c0 + cc];
      tl[rr + i * 16][cc + 0] = v.x; tl[rr + i * 16][cc + 1] = v.y;
      tl[rr + i * 16][cc + 2] = v.z; tl[rr + i * 16][cc + 3] = v.w;
    }
  }
  __syncthreads();
  {
    const int r4 = (tid & 15) * 4;
    #pragma unroll
    for (int i = 0; i < 4; ++i) {
      const int cr = i * 16 + (tid >> 4);
      uint2 o;
      o.x = (unsigned)f2bf(tl[r4 + 0][cr]) | ((unsigned)f2bf(tl[r4 + 1][cr]) << 16);
      o.y = (unsigned)f2bf(tl[r4 + 2][cr]) | ((unsigned)f2bf(tl[r4 + 3][cr]) << 16);
      *(uint2*)&out[(size_t)(c0 + cr) * R + r0 + r4] = o;
    }
  }
}

// ---------- GEMM1: 128x128 tile, 4 waves in 2x2 (64x64 quadrant each),
// BK=64, split-K=8 with z = XCD (bid&7). global_load_lds both operands,
// double-buffered LDS, one barrier per iter. bf16 partials P[z]. ----------
template <int KSLICE>
__global__ __launch_bounds__(256, 2)
void mfma_gemm(const unsigned short* __restrict__ A,
               const unsigned short* __restrict__ Bt,
               unsigned short* __restrict__ P, int K) {
  __shared__ __align__(16) unsigned short smem[2][2 * 128 * 64];  // 2 x 32 KB

  const int tid = threadIdx.x;
  const int w = tid >> 6, l = tid & 63;
  const int bid = blockIdx.x;
  const int z = bid & 7, t = bid >> 3;
  const int m0 = (t >> 3) * 128, n0 = (t & 7) * 128;
  const int kb = z * KSLICE;

  f32x4 acc[4][4] = {};

  constexpr int NIT = KSLICE / 64;

  auto stage = [&](int buf, int it) {
    const int k0 = kb + it * 64;
    unsigned short* LA = smem[buf];
    unsigned short* LB = smem[buf] + 128 * 64;
    #pragma unroll
    for (int i = 0; i < 4; ++i) {
      const int c = i * 256 + tid, row = c >> 3, kc = c & 7;
      const int kcg = kc ^ (row & 7);
      __builtin_amdgcn_global_load_lds(
          (const __attribute__((address_space(1))) unsigned int*)(A + (size_t)(m0 + row) * K + k0 + kcg * 8),
          (__attribute__((address_space(3))) unsigned int*)&LA[c * 8], 16, 0, 0);
    }
    #pragma unroll
    for (int i = 0; i < 4; ++i) {
      const int c = i * 256 + tid, row = c >> 3, kc = c & 7;
      const int kcg = kc ^ (row & 7);
      __builtin_amdgcn_global_load_lds(
          (const __attribute__((address_space(1))) unsigned int*)(Bt + (size_t)(n0 + row) * K + k0 + kcg * 8),
          (__attribute__((address_space(3))) unsigned int*)&LB[c * 8], 16, 0, 0);
    }
  };

  stage(0, 0);
  int cur = 0;
  for (int it = 0; it < NIT; ++it) {
    __syncthreads();                 // drains vmcnt: buf[cur] ready; prior readers done
    if (it + 1 < NIT) stage(cur ^ 1, it + 1);   // async prefetch next tile

    const unsigned short* LA = smem[cur];
    const unsigned short* LB = smem[cur] + 128 * 64;
    #pragma unroll
    for (int s = 0; s < 2; ++s) {
      const int kcq = s * 4 + (l >> 4);
      bf16x8 af[4], bfr[4];
      #pragma unroll
      for (int i = 0; i < 4; ++i) {
        const int r = (w >> 1) * 64 + i * 16 + (l & 15);
        const int kca = kcq ^ (r & 7);
        af[i] = __builtin_bit_cast(bf16x8, *(const s16x8*)&LA[(r * 8 + kca) * 8]);
      }
      #pragma unroll
      for (int j = 0; j < 4; ++j) {
        const int rr = (w & 1) * 64 + j * 16 + (l & 15);
        const int kcb = kcq ^ (rr & 7);
        bfr[j] = __builtin_bit_cast(bf16x8, *(const s16x8*)&LB[(rr * 8 + kcb) * 8]);
      }
      #pragma unroll
      for (int i = 0; i < 4; ++i)
        #pragma unroll
        for (int j = 0; j < 4; ++j)
          acc[i][j] = __builtin_amdgcn_mfma_f32_16x16x32_bf16(af[i], bfr[j], acc[i][j], 0, 0, 0);
    }
    cur ^= 1;
  }

  unsigned short* Pz = P + (size_t)z * MN;
  #pragma unroll
  for (int i = 0; i < 4; ++i) {
    #pragma unroll
    for (int r = 0; r < 4; ++r) {
      const int m = m0 + (w >> 1) * 64 + i * 16 + (l >> 4) * 4 + r;
      #pragma unroll
      for (int j = 0; j < 4; ++j) {
        const int n = n0 + (w & 1) * 64 + j * 16 + (l & 15);
        Pz[(size_t)m * DO + n] = f2bf(acc[i][j][r]);
      }
    }
  }
}

// ---------- combine1: H = relu(sum_z bf16 P[z] + b1) -> bf16 (uint4 loads) ----------
__global__ __launch_bounds__(256)
void combine1(const unsigned short* __restrict__ P, const float* __restrict__ bias,
              unsigned short* __restrict__ out) {
  const int t = threadIdx.x;
  const int row = blockIdx.x * 2 + (t >> 7);
  const int col = (t & 127) * 8;
  const size_t base = (size_t)row * DO + col;
  float s[8] = {};
  #pragma unroll
  for (int c = 0; c < 8; ++c) {
    const uint4 wv = *(const uint4*)&P[(size_t)c * MN + base];
    s[0] += bf2f(wv.x & 0xFFFFu); s[1] += bf2f(wv.x >> 16);
    s[2] += bf2f(wv.y & 0xFFFFu); s[3] += bf2f(wv.y >> 16);
    s[4] += bf2f(wv.z & 0xFFFFu); s[5] += bf2f(wv.z >> 16);
    s[6] += bf2f(wv.w & 0xFFFFu); s[7] += bf2f(wv.w >> 16);
  }
  const f32x4 b0 = *(const f32x4*)&bias[col];
  const f32x4 b1v = *(const f32x4*)&bias[col + 4];
  #pragma unroll
  for (int i = 0; i < 4; ++i) s[i] = fmaxf(s[i] + b0[i], 0.f);
  #pragma unroll
  for (int i = 0; i < 4; ++i) s[4 + i] = fmaxf(s[4 + i] + b1v[i], 0.f);
  uint4 o;
  o.x = (unsigned)f2bf(s[0]) | ((unsigned)f2bf(s[1]) << 16);
  o.y = (unsigned)f2bf(s[2]) | ((unsigned)f2bf(s[3]) << 16);
  o.z = (unsigned)f2bf(s[4]) | ((unsigned)f2bf(s[5]) << 16);
  o.w = (unsigned)f2bf(s[6]) | ((unsigned)f2bf(s[7]) << 16);
  *(uint4*)&out[base] = o;
}

// ---------- GEMM2 (full-K): 64x64 tile, in-block 4-wave k-split, BK=128,
// double-buffered LDS 2-phase pipeline, LDS tree-reduce,
// epilogue writes E = sum + b2 directly (fp32). ----------
__global__ __launch_bounds__(256, 2)
void gemm2_full(const unsigned short* __restrict__ A,
                const unsigned short* __restrict__ Bt,
                const float* __restrict__ b2, float* __restrict__ E) {
  __shared__ __align__(16) unsigned short smem[2][2 * 64 * 128];  // 2 x 32 KB

  const int tid = threadIdx.x;
  const int w = tid >> 6, l = tid & 63;
  const int bid = blockIdx.x;
  const int m0 = (bid >> 4) * 64, n0 = (bid & 15) * 64;

  f32x4 acc[4][4] = {};

  auto stage = [&](int buf, int it) {
    const int k0 = it * 128;
    unsigned short* LA = smem[buf];
    unsigned short* LB = smem[buf] + 64 * 128;
    #pragma unroll
    for (int i = 0; i < 4; ++i) {
      const int c = i * 256 + tid, m = c >> 4, kc = c & 15;
      const int kcg = (kc & 8) | ((kc & 7) ^ (m & 7));
      __builtin_amdgcn_global_load_lds(
          (const __attribute__((address_space(1))) unsigned int*)(A + (size_t)(m0 + m) * DO + k0 + kcg * 8),
          (__attribute__((address_space(3))) unsigned int*)&LA[c * 8], 16, 0, 0);
    }
    #pragma unroll
    for (int i = 0; i < 4; ++i) {
      const int c = i * 256 + tid, n = c >> 4, kc = c & 15;
      const int kcg = (kc & 8) | ((kc & 7) ^ (n & 7));
      __builtin_amdgcn_global_load_lds(
          (const __attribute__((address_space(1))) unsigned int*)(Bt + (size_t)(n0 + n) * DO + k0 + kcg * 8),
          (__attribute__((address_space(3))) unsigned int*)&LB[c * 8], 16, 0, 0);
    }
  };

  stage(0, 0);
  int cur = 0;
  for (int it = 0; it < 8; ++it) {  // K=1024, BK=128
    __syncthreads();
    if (it + 1 < 8) stage(cur ^ 1, it + 1);

    const unsigned short* LA = smem[cur];
    const unsigned short* LB = smem[cur] + 64 * 128;
    const int kcq = w * 4 + (l >> 4);
    bf16x8 af[4], bfr[4];
    #pragma unroll
    for (int i = 0; i < 4; ++i) {
      const int r = i * 16 + (l & 15);
      const int kca = (kcq & 8) | ((kcq & 7) ^ (r & 7));
      af[i]  = __builtin_bit_cast(bf16x8, *(const s16x8*)&LA[(r * 16 + kca) * 8]);
      bfr[i] = __builtin_bit_cast(bf16x8, *(const s16x8*)&LB[(r * 16 + kca) * 8]);
    }
    #pragma unroll
    for (int i = 0; i < 4; ++i)
      #pragma unroll
      for (int j = 0; j < 4; ++j)
        acc[i][j] = __builtin_amdgcn_mfma_f32_16x16x32_bf16(af[i], bfr[j], acc[i][j], 0, 0, 0);
    cur ^= 1;
  }
  __syncthreads();

  float* red = (float*)smem;
  if (w >= 2) {
    #pragma unroll
    for (int i = 0; i < 4; ++i)
      #pragma unroll
      for (int j = 0; j < 4; ++j)
        *(f32x4*)&red[(w - 2) * 4096 + ((i * 4 + j) * 64 + l) * 4] = acc[i][j];
  }
  __syncthreads();
  if (w < 2) {
    #pragma unroll
    for (int i = 0; i < 4; ++i)
      #pragma unroll
      for (int j = 0; j < 4; ++j)
        acc[i][j] += *(const f32x4*)&red[w * 4096 + ((i * 4 + j) * 64 + l) * 4];
  }
  __syncthreads();
  if (w == 1) {
    #pragma unroll
    for (int i = 0; i < 2; ++i)
      #pragma unroll
      for (int j = 0; j < 4; ++j)
        *(f32x4*)&red[((i * 4 + j) * 64 + l) * 4] = acc[i][j];
  } else if (w == 0) {
    #pragma unroll
    for (int i = 0; i < 2; ++i)
      #pragma unroll
      for (int j = 0; j < 4; ++j)
        *(f32x4*)&red[2048 + ((i * 4 + j) * 64 + l) * 4] = acc[i + 2][j];
  }
  __syncthreads();
  if (w >= 2) return;

  if (w == 0) {
    #pragma unroll
    for (int i = 0; i < 2; ++i) {
      #pragma unroll
      for (int j = 0; j < 4; ++j)
        acc[i][j] += *(const f32x4*)&red[((i * 4 + j) * 64 + l) * 4];
      #pragma unroll
      for (int r = 0; r < 4; ++r) {
        const int m = m0 + i * 16 + (l >> 4) * 4 + r;
        #pragma unroll
        for (int j = 0; j < 4; ++j) {
          const int n = n0 + j * 16 + (l & 15);
          E[(size_t)m * DO + n] = acc[i][j][r] + b2[n];
        }
      }
    }
  } else {
    #pragma unroll
    for (int i = 0; i < 2; ++i) {
      #pragma unroll
      for (int j = 0; j < 4; ++j)
        acc[i + 2][j] += *(const f32x4*)&red[2048 + ((i * 4 + j) * 64 + l) * 4];
      #pragma unroll
      for (int r = 0; r < 4; ++r) {
        const int m = m0 + (i + 2) * 16 + (l >> 4) * 4 + r;
        #pragma unroll
        for (int j = 0; j < 4; ++j) {
          const int n = n0 + j * 16 + (l & 15);
          E[(size_t)m * DO + n] = acc[i + 2][j][r] + b2[n];
        }
      }
    }
  }
}

// ---------- scores: d-split partials (8 slices, 2 chunks of 64 each).
// ls layout de-conflicted: row width 140, octet tl stored at base
// f(tl) = tl*8 + (tl>>2)*4  (write col c(l) = l + (l>>5)*4).
// f(tl) mod 32 takes 8 residues -> ds_read_b128 2-way (free, m136),
// vs 4-way at the old tl*8 layout. 16B alignment preserved (140*4, f*4 = 0 mod 16). ----------
__global__ __launch_bounds__(256)
void score_partial(const float* __restrict__ E, const float* __restrict__ labels,
                   float* __restrict__ SP) {
  __shared__ float es[64][33];   // [d][b]
  __shared__ float ls[64][140];  // [d][swizzled l]
  const int tid = threadIdx.x;
  const int b0 = blockIdx.x * 32;

  const int tb = tid & 15;   // b-pair
  const int tl = tid >> 4;   // label-octet
  const int fb = tl * 8 + (tl >> 2) * 4;   // swizzled octet base
  float acc[2][8] = {};

  #pragma unroll
  for (int ch = 0; ch < 2; ++ch) {
    const int d0 = blockIdx.y * 128 + ch * 64;
    if (ch) __syncthreads();   // previous chunk's readers done before overwrite

    #pragma unroll
    for (int i = 0; i < 2; ++i) {
      const int fi = tid + i * 256;
      const int b = fi >> 4, dq = fi & 15;
      const float4 v = *(const float4*)&E[(size_t)(b0 + b) * DO + d0 + dq * 4];
      es[dq * 4 + 0][b] = v.x; es[dq * 4 + 1][b] = v.y;
      es[dq * 4 + 2][b] = v.z; es[dq * 4 + 3][b] = v.w;
    }
    #pragma unroll
    for (int i = 0; i < 8; ++i) {
      const int fi = tid + i * 256;
      const int lr = fi >> 4, dq = fi & 15;
      const int cc = lr + ((lr >> 5) << 2);   // swizzled column
      const float4 v = *(const float4*)&labels[(size_t)lr * DO + d0 + dq * 4];
      ls[dq * 4 + 0][cc] = v.x; ls[dq * 4 + 1][cc] = v.y;
      ls[dq * 4 + 2][cc] = v.z; ls[dq * 4 + 3][cc] = v.w;
    }
    __syncthreads();

    for (int dd = 0; dd < 64; ++dd) {
      const float e0 = es[dd][tb * 2 + 0];
      const float e1 = es[dd][tb * 2 + 1];
      const float4 l0 = *(const float4*)&ls[dd][fb];
      const float4 l1 = *(const float4*)&ls[dd][fb + 4];
      const float lv[8] = {l0.x, l0.y, l0.z, l0.w, l1.x, l1.y, l1.z, l1.w};
      #pragma unroll
      for (int j = 0; j < 8; ++j) {
        float t0 = fmaxf(lv[j] - e0, 0.f); acc[0][j] = fmaf(t0, t0, acc[0][j]);
        float t1 = fmaxf(lv[j] - e1, 0.f); acc[1][j] = fmaf(t1, t1, acc[1][j]);
      }
    }
  }

  float* SPz = SP + (size_t)blockIdx.y * (Bn * NL);
  #pragma unroll
  for (int i = 0; i < 2; ++i) {
    const size_t base = (size_t)(b0 + tb * 2 + i) * NL + tl * 8;
    float4 v0 = {acc[i][0], acc[i][1], acc[i][2], acc[i][3]};
    float4 v1 = {acc[i][4], acc[i][5], acc[i][6], acc[i][7]};
    *(float4*)&SPz[base]     = v0;
    *(float4*)&SPz[base + 4] = v1;
  }
}

__global__ __launch_bounds__(256)
void score_reduce(const float* __restrict__ SP, float* __restrict__ out) {
  const size_t i4 = (size_t)blockIdx.x * 256 + threadIdx.x;
  f32x4 s = ((const f32x4*)SP)[i4];
  #pragma unroll
  for (int c = 1; c < 8; ++c) s += ((const f32x4*)SP)[(size_t)c * 32768 + i4];
  f32x4 o = {-sqrtf(s[0]), -sqrtf(s[1]), -sqrtf(s[2]), -sqrtf(s[3])};
  ((f32x4*)out)[i4] = o;
}

extern "C" void kernel_launch(void* const* d_in, const int* in_sizes, int n_in,
                              void* d_out, int out_size, void* d_ws, size_t ws_size,
                              hipStream_t stream) {
  const float* sbj  = (const float*)d_in[0];
  const float* obj  = (const float*)d_in[1];
  const float* W1   = (const float*)d_in[2];
  const float* b1   = (const float*)d_in[3];
  const float* W2   = (const float*)d_in[4];
  const float* b2   = (const float*)d_in[5];
  const float* labs = (const float*)d_in[6];
  float* scores = (float*)d_out;
  char* ws = (char*)d_ws;

  // Layout (MB): Abf [0,8)  W1t [8,16)  W2t [16,18)  H [18,20)  E [20,24)
  //              P [24,40) = 8 x 2 MB bf16    SP [40,44)
  unsigned short* Abf = (unsigned short*)(ws);
  unsigned short* W1t = (unsigned short*)(ws + (8ull << 20));
  unsigned short* W2t = (unsigned short*)(ws + (16ull << 20));
  unsigned short* H   = (unsigned short*)(ws + (18ull << 20));
  float* E  = (float*)(ws + (20ull << 20));
  unsigned short* P = (unsigned short*)(ws + (24ull << 20));
  float* SP = (float*)(ws + (40ull << 20));

  dim3 blk(256);
  prep<<<dim3(2048 + 1280), blk, 0, stream>>>(sbj, obj, W1, W2, Abf, W1t, W2t);

  // GEMM1: K=4096, 128^2 tiles, split-K=8 (KSLICE=512), z = XCD, bf16 partials
  mfma_gemm<512><<<dim3(512), blk, 0, stream>>>(Abf, W1t, P, K1);
  combine1<<<dim3(512), blk, 0, stream>>>(P, b1, H);
  // GEMM2: full-K, direct E output (no partials)
  gemm2_full<<<dim3(256), blk, 0, stream>>>(H, W2t, b2, E);
  // scores: 8 d-slices (2 chunks of 64 per block), de-conflicted ls
  score_partial<<<dim3(32, 8), blk, 0, stream>>>(E, labs, SP);
  score_reduce<<<dim3(128), blk, 0, stream>>>(SP, scores);
}

// Round 6
// 131.467 us; speedup vs baseline: 2.8247x; 1.0239x over previous
//
#include <hip/hip_runtime.h>
#include <math.h>

constexpr int Bn = 1024, DH = 2048, K1 = 4096, DO = 1024, NL = 128;
constexpr int MN = Bn * DO;  // 1M elements

typedef __bf16 bf16x8 __attribute__((ext_vector_type(8)));
typedef short  s16x8  __attribute__((ext_vector_type(8)));
typedef float  f32x4  __attribute__((ext_vector_type(4)));

__device__ __forceinline__ unsigned short f2bf(float f) {
  union { float f; unsigned u; } v; v.f = f;
  unsigned r = v.u + 0x7FFFu + ((v.u >> 16) & 1u);  // RNE
  return (unsigned short)(r >> 16);
}
__device__ __forceinline__ float bf2f(unsigned h) {
  union { unsigned u; float f; } v; v.u = h << 16; return v.f;
}

// ---------- prep: concat+relu+bf16 (blocks 0..2047) + W1/W2 transposes ----------
__global__ __launch_bounds__(256)
void prep(const float* __restrict__ sbj, const float* __restrict__ obj,
          const float* __restrict__ W1, const float* __restrict__ W2,
          unsigned short* __restrict__ Abf,
          unsigned short* __restrict__ W1t, unsigned short* __restrict__ W2t) {
  const int tid = threadIdx.x;
  if (blockIdx.x < 2048) {
    const int t = blockIdx.x * 256 + tid;
    const int m = t >> 9;
    const int k = (t & 511) << 3;
    const float* src = (k < DH) ? sbj + (size_t)m * DH + k
                                : obj + (size_t)m * DH + (k - DH);
    const float4 a = ((const float4*)src)[0];
    const float4 b = ((const float4*)src)[1];
    uint4 o;
    o.x = (unsigned)f2bf(fmaxf(a.x, 0.f)) | ((unsigned)f2bf(fmaxf(a.y, 0.f)) << 16);
    o.y = (unsigned)f2bf(fmaxf(a.z, 0.f)) | ((unsigned)f2bf(fmaxf(a.w, 0.f)) << 16);
    o.z = (unsigned)f2bf(fmaxf(b.x, 0.f)) | ((unsigned)f2bf(fmaxf(b.y, 0.f)) << 16);
    o.w = (unsigned)f2bf(fmaxf(b.z, 0.f)) | ((unsigned)f2bf(fmaxf(b.w, 0.f)) << 16);
    *(uint4*)&Abf[(size_t)m * K1 + k] = o;
    return;
  }
  __shared__ float tl[64][65];
  const int tb = blockIdx.x - 2048;
  int by = tb >> 4;
  const int c0 = (tb & 15) * 64;
  const float* in; unsigned short* out; int R;
  if (by < 64) { in = W1; out = W1t; R = K1; }
  else         { in = W2; out = W2t; R = DO; by -= 64; }
  const int r0 = by * 64;
  {
    const int rr = tid >> 4, cc = (tid & 15) * 4;
    #pragma unroll
    for (int i = 0; i < 4; ++i) {
      const float4 v = *(const float4*)&in[(size_t)(r0 + rr + i * 16) * DO + c0 + cc];
      tl[rr + i * 16][cc + 0] = v.x; tl[rr + i * 16][cc + 1] = v.y;
      tl[rr + i * 16][cc + 2] = v.z; tl[rr + i * 16][cc + 3] = v.w;
    }
  }
  __syncthreads();
  {
    const int r4 = (tid & 15) * 4;
    #pragma unroll
    for (int i = 0; i < 4; ++i) {
      const int cr = i * 16 + (tid >> 4);
      uint2 o;
      o.x = (unsigned)f2bf(tl[r4 + 0][cr]) | ((unsigned)f2bf(tl[r4 + 1][cr]) << 16);
      o.y = (unsigned)f2bf(tl[r4 + 2][cr]) | ((unsigned)f2bf(tl[r4 + 3][cr]) << 16);
      *(uint2*)&out[(size_t)(c0 + cr) * R + r0 + r4] = o;
    }
  }
}

// ---------- GEMM1: 128x128 tile, 4 waves in 2x2 (64x64 quadrant each),
// BK=64, split-K=8 with z = XCD (bid&7). global_load_lds both operands,
// double-buffered LDS, one barrier per iter. bf16 partials P[z]. ----------
template <int KSLICE>
__global__ __launch_bounds__(256, 2)
void mfma_gemm(const unsigned short* __restrict__ A,
               const unsigned short* __restrict__ Bt,
               unsigned short* __restrict__ P, int K) {
  __shared__ __align__(16) unsigned short smem[2][2 * 128 * 64];  // 2 x 32 KB

  const int tid = threadIdx.x;
  const int w = tid >> 6, l = tid & 63;
  const int bid = blockIdx.x;
  const int z = bid & 7, t = bid >> 3;
  const int m0 = (t >> 3) * 128, n0 = (t & 7) * 128;
  const int kb = z * KSLICE;

  f32x4 acc[4][4] = {};

  constexpr int NIT = KSLICE / 64;

  auto stage = [&](int buf, int it) {
    const int k0 = kb + it * 64;
    unsigned short* LA = smem[buf];
    unsigned short* LB = smem[buf] + 128 * 64;
    #pragma unroll
    for (int i = 0; i < 4; ++i) {
      const int c = i * 256 + tid, row = c >> 3, kc = c & 7;
      const int kcg = kc ^ (row & 7);
      __builtin_amdgcn_global_load_lds(
          (const __attribute__((address_space(1))) unsigned int*)(A + (size_t)(m0 + row) * K + k0 + kcg * 8),
          (__attribute__((address_space(3))) unsigned int*)&LA[c * 8], 16, 0, 0);
    }
    #pragma unroll
    for (int i = 0; i < 4; ++i) {
      const int c = i * 256 + tid, row = c >> 3, kc = c & 7;
      const int kcg = kc ^ (row & 7);
      __builtin_amdgcn_global_load_lds(
          (const __attribute__((address_space(1))) unsigned int*)(Bt + (size_t)(n0 + row) * K + k0 + kcg * 8),
          (__attribute__((address_space(3))) unsigned int*)&LB[c * 8], 16, 0, 0);
    }
  };

  stage(0, 0);
  int cur = 0;
  for (int it = 0; it < NIT; ++it) {
    __syncthreads();                 // drains vmcnt: buf[cur] ready; prior readers done
    if (it + 1 < NIT) stage(cur ^ 1, it + 1);   // async prefetch next tile

    const unsigned short* LA = smem[cur];
    const unsigned short* LB = smem[cur] + 128 * 64;
    #pragma unroll
    for (int s = 0; s < 2; ++s) {
      const int kcq = s * 4 + (l >> 4);
      bf16x8 af[4], bfr[4];
      #pragma unroll
      for (int i = 0; i < 4; ++i) {
        const int r = (w >> 1) * 64 + i * 16 + (l & 15);
        const int kca = kcq ^ (r & 7);
        af[i] = __builtin_bit_cast(bf16x8, *(const s16x8*)&LA[(r * 8 + kca) * 8]);
      }
      #pragma unroll
      for (int j = 0; j < 4; ++j) {
        const int rr = (w & 1) * 64 + j * 16 + (l & 15);
        const int kcb = kcq ^ (rr & 7);
        bfr[j] = __builtin_bit_cast(bf16x8, *(const s16x8*)&LB[(rr * 8 + kcb) * 8]);
      }
      #pragma unroll
      for (int i = 0; i < 4; ++i)
        #pragma unroll
        for (int j = 0; j < 4; ++j)
          acc[i][j] = __builtin_amdgcn_mfma_f32_16x16x32_bf16(af[i], bfr[j], acc[i][j], 0, 0, 0);
    }
    cur ^= 1;
  }

  unsigned short* Pz = P + (size_t)z * MN;
  #pragma unroll
  for (int i = 0; i < 4; ++i) {
    #pragma unroll
    for (int r = 0; r < 4; ++r) {
      const int m = m0 + (w >> 1) * 64 + i * 16 + (l >> 4) * 4 + r;
      #pragma unroll
      for (int j = 0; j < 4; ++j) {
        const int n = n0 + (w & 1) * 64 + j * 16 + (l & 15);
        Pz[(size_t)m * DO + n] = f2bf(acc[i][j][r]);
      }
    }
  }
}

// ---------- combine1: H = relu(sum_z bf16 P[z] + b1) -> bf16 (uint4 loads) ----------
__global__ __launch_bounds__(256)
void combine1(const unsigned short* __restrict__ P, const float* __restrict__ bias,
              unsigned short* __restrict__ out) {
  const int t = threadIdx.x;
  const int row = blockIdx.x * 2 + (t >> 7);
  const int col = (t & 127) * 8;
  const size_t base = (size_t)row * DO + col;
  float s[8] = {};
  #pragma unroll
  for (int c = 0; c < 8; ++c) {
    const uint4 wv = *(const uint4*)&P[(size_t)c * MN + base];
    s[0] += bf2f(wv.x & 0xFFFFu); s[1] += bf2f(wv.x >> 16);
    s[2] += bf2f(wv.y & 0xFFFFu); s[3] += bf2f(wv.y >> 16);
    s[4] += bf2f(wv.z & 0xFFFFu); s[5] += bf2f(wv.z >> 16);
    s[6] += bf2f(wv.w & 0xFFFFu); s[7] += bf2f(wv.w >> 16);
  }
  const f32x4 b0 = *(const f32x4*)&bias[col];
  const f32x4 b1v = *(const f32x4*)&bias[col + 4];
  #pragma unroll
  for (int i = 0; i < 4; ++i) s[i] = fmaxf(s[i] + b0[i], 0.f);
  #pragma unroll
  for (int i = 0; i < 4; ++i) s[4 + i] = fmaxf(s[4 + i] + b1v[i], 0.f);
  uint4 o;
  o.x = (unsigned)f2bf(s[0]) | ((unsigned)f2bf(s[1]) << 16);
  o.y = (unsigned)f2bf(s[2]) | ((unsigned)f2bf(s[3]) << 16);
  o.z = (unsigned)f2bf(s[4]) | ((unsigned)f2bf(s[5]) << 16);
  o.w = (unsigned)f2bf(s[6]) | ((unsigned)f2bf(s[7]) << 16);
  *(uint4*)&out[base] = o;
}

// ---------- GEMM2 (full-K): 64x64 tile, in-block 4-wave k-split, BK=128,
// double-buffered LDS 2-phase pipeline, LDS tree-reduce,
// epilogue writes E = sum + b2 directly (fp32). ----------
__global__ __launch_bounds__(256, 2)
void gemm2_full(const unsigned short* __restrict__ A,
                const unsigned short* __restrict__ Bt,
                const float* __restrict__ b2, float* __restrict__ E) {
  __shared__ __align__(16) unsigned short smem[2][2 * 64 * 128];  // 2 x 32 KB

  const int tid = threadIdx.x;
  const int w = tid >> 6, l = tid & 63;
  const int bid = blockIdx.x;
  const int m0 = (bid >> 4) * 64, n0 = (bid & 15) * 64;

  f32x4 acc[4][4] = {};

  auto stage = [&](int buf, int it) {
    const int k0 = it * 128;
    unsigned short* LA = smem[buf];
    unsigned short* LB = smem[buf] + 64 * 128;
    #pragma unroll
    for (int i = 0; i < 4; ++i) {
      const int c = i * 256 + tid, m = c >> 4, kc = c & 15;
      const int kcg = (kc & 8) | ((kc & 7) ^ (m & 7));
      __builtin_amdgcn_global_load_lds(
          (const __attribute__((address_space(1))) unsigned int*)(A + (size_t)(m0 + m) * DO + k0 + kcg * 8),
          (__attribute__((address_space(3))) unsigned int*)&LA[c * 8], 16, 0, 0);
    }
    #pragma unroll
    for (int i = 0; i < 4; ++i) {
      const int c = i * 256 + tid, n = c >> 4, kc = c & 15;
      const int kcg = (kc & 8) | ((kc & 7) ^ (n & 7));
      __builtin_amdgcn_global_load_lds(
          (const __attribute__((address_space(1))) unsigned int*)(Bt + (size_t)(n0 + n) * DO + k0 + kcg * 8),
          (__attribute__((address_space(3))) unsigned int*)&LB[c * 8], 16, 0, 0);
    }
  };

  stage(0, 0);
  int cur = 0;
  for (int it = 0; it < 8; ++it) {  // K=1024, BK=128
    __syncthreads();
    if (it + 1 < 8) stage(cur ^ 1, it + 1);

    const unsigned short* LA = smem[cur];
    const unsigned short* LB = smem[cur] + 64 * 128;
    const int kcq = w * 4 + (l >> 4);
    bf16x8 af[4], bfr[4];
    #pragma unroll
    for (int i = 0; i < 4; ++i) {
      const int r = i * 16 + (l & 15);
      const int kca = (kcq & 8) | ((kcq & 7) ^ (r & 7));
      af[i]  = __builtin_bit_cast(bf16x8, *(const s16x8*)&LA[(r * 16 + kca) * 8]);
      bfr[i] = __builtin_bit_cast(bf16x8, *(const s16x8*)&LB[(r * 16 + kca) * 8]);
    }
    #pragma unroll
    for (int i = 0; i < 4; ++i)
      #pragma unroll
      for (int j = 0; j < 4; ++j)
        acc[i][j] = __builtin_amdgcn_mfma_f32_16x16x32_bf16(af[i], bfr[j], acc[i][j], 0, 0, 0);
    cur ^= 1;
  }
  __syncthreads();

  float* red = (float*)smem;
  if (w >= 2) {
    #pragma unroll
    for (int i = 0; i < 4; ++i)
      #pragma unroll
      for (int j = 0; j < 4; ++j)
        *(f32x4*)&red[(w - 2) * 4096 + ((i * 4 + j) * 64 + l) * 4] = acc[i][j];
  }
  __syncthreads();
  if (w < 2) {
    #pragma unroll
    for (int i = 0; i < 4; ++i)
      #pragma unroll
      for (int j = 0; j < 4; ++j)
        acc[i][j] += *(const f32x4*)&red[w * 4096 + ((i * 4 + j) * 64 + l) * 4];
  }
  __syncthreads();
  if (w == 1) {
    #pragma unroll
    for (int i = 0; i < 2; ++i)
      #pragma unroll
      for (int j = 0; j < 4; ++j)
        *(f32x4*)&red[((i * 4 + j) * 64 + l) * 4] = acc[i][j];
  } else if (w == 0) {
    #pragma unroll
    for (int i = 0; i < 2; ++i)
      #pragma unroll
      for (int j = 0; j < 4; ++j)
        *(f32x4*)&red[2048 + ((i * 4 + j) * 64 + l) * 4] = acc[i + 2][j];
  }
  __syncthreads();
  if (w >= 2) return;

  if (w == 0) {
    #pragma unroll
    for (int i = 0; i < 2; ++i) {
      #pragma unroll
      for (int j = 0; j < 4; ++j)
        acc[i][j] += *(const f32x4*)&red[((i * 4 + j) * 64 + l) * 4];
      #pragma unroll
      for (int r = 0; r < 4; ++r) {
        const int m = m0 + i * 16 + (l >> 4) * 4 + r;
        #pragma unroll
        for (int j = 0; j < 4; ++j) {
          const int n = n0 + j * 16 + (l & 15);
          E[(size_t)m * DO + n] = acc[i][j][r] + b2[n];
        }
      }
    }
  } else {
    #pragma unroll
    for (int i = 0; i < 2; ++i) {
      #pragma unroll
      for (int j = 0; j < 4; ++j)
        acc[i + 2][j] += *(const f32x4*)&red[2048 + ((i * 4 + j) * 64 + l) * 4];
      #pragma unroll
      for (int r = 0; r < 4; ++r) {
        const int m = m0 + (i + 2) * 16 + (l >> 4) * 4 + r;
        #pragma unroll
        for (int j = 0; j < 4; ++j) {
          const int n = n0 + j * 16 + (l & 15);
          E[(size_t)m * DO + n] = acc[i + 2][j][r] + b2[n];
        }
      }
    }
  }
}

// ---------- scores: d-split partials (8 slices, 2 chunks of 64 each).
// b-chunks of 16 rows -> grid (64,8) = 512 blocks = 2 blocks/CU (2 waves/SIMD):
// latency-regime fix — second resident block hides LDS/global latency.
// Per thread: 1 b-row x 8 labels. ls keeps the de-conflicted 140-wide layout. ----------
__global__ __launch_bounds__(256, 2)
void score_partial(const float* __restrict__ E, const float* __restrict__ labels,
                   float* __restrict__ SP) {
  __shared__ float es[64][17];   // [d][b]
  __shared__ float ls[64][140];  // [d][swizzled l]
  const int tid = threadIdx.x;
  const int b0 = blockIdx.x * 16;

  const int tb = tid & 15;   // b-row
  const int tl = tid >> 4;   // label-octet
  const int fb = tl * 8 + (tl >> 2) * 4;   // swizzled octet base
  float acc[8] = {};

  #pragma unroll
  for (int ch = 0; ch < 2; ++ch) {
    const int d0 = blockIdx.y * 128 + ch * 64;
    if (ch) __syncthreads();   // previous chunk's readers done before overwrite

    {
      const int b = tid >> 4, dq = tid & 15;
      const float4 v = *(const float4*)&E[(size_t)(b0 + b) * DO + d0 + dq * 4];
      es[dq * 4 + 0][b] = v.x; es[dq * 4 + 1][b] = v.y;
      es[dq * 4 + 2][b] = v.z; es[dq * 4 + 3][b] = v.w;
    }
    #pragma unroll
    for (int i = 0; i < 8; ++i) {
      const int fi = tid + i * 256;
      const int lr = fi >> 4, dq = fi & 15;
      const int cc = lr + ((lr >> 5) << 2);   // swizzled column
      const float4 v = *(const float4*)&labels[(size_t)lr * DO + d0 + dq * 4];
      ls[dq * 4 + 0][cc] = v.x; ls[dq * 4 + 1][cc] = v.y;
      ls[dq * 4 + 2][cc] = v.z; ls[dq * 4 + 3][cc] = v.w;
    }
    __syncthreads();

    for (int dd = 0; dd < 64; ++dd) {
      const float e0 = es[dd][tb];
      const float4 l0 = *(const float4*)&ls[dd][fb];
      const float4 l1 = *(const float4*)&ls[dd][fb + 4];
      const float lv[8] = {l0.x, l0.y, l0.z, l0.w, l1.x, l1.y, l1.z, l1.w};
      #pragma unroll
      for (int j = 0; j < 8; ++j) {
        float t0 = fmaxf(lv[j] - e0, 0.f); acc[j] = fmaf(t0, t0, acc[j]);
      }
    }
  }

  float* SPz = SP + (size_t)blockIdx.y * (Bn * NL);
  const size_t base = (size_t)(b0 + tb) * NL + tl * 8;
  float4 v0 = {acc[0], acc[1], acc[2], acc[3]};
  float4 v1 = {acc[4], acc[5], acc[6], acc[7]};
  *(float4*)&SPz[base]     = v0;
  *(float4*)&SPz[base + 4] = v1;
}

__global__ __launch_bounds__(256)
void score_reduce(const float* __restrict__ SP, float* __restrict__ out) {
  const size_t i4 = (size_t)blockIdx.x * 256 + threadIdx.x;
  f32x4 s = ((const f32x4*)SP)[i4];
  #pragma unroll
  for (int c = 1; c < 8; ++c) s += ((const f32x4*)SP)[(size_t)c * 32768 + i4];
  f32x4 o = {-sqrtf(s[0]), -sqrtf(s[1]), -sqrtf(s[2]), -sqrtf(s[3])};
  ((f32x4*)out)[i4] = o;
}

extern "C" void kernel_launch(void* const* d_in, const int* in_sizes, int n_in,
                              void* d_out, int out_size, void* d_ws, size_t ws_size,
                              hipStream_t stream) {
  const float* sbj  = (const float*)d_in[0];
  const float* obj  = (const float*)d_in[1];
  const float* W1   = (const float*)d_in[2];
  const float* b1   = (const float*)d_in[3];
  const float* W2   = (const float*)d_in[4];
  const float* b2   = (const float*)d_in[5];
  const float* labs = (const float*)d_in[6];
  float* scores = (float*)d_out;
  char* ws = (char*)d_ws;

  // Layout (MB): Abf [0,8)  W1t [8,16)  W2t [16,18)  H [18,20)  E [20,24)
  //              P [24,40) = 8 x 2 MB bf16    SP [40,44)
  unsigned short* Abf = (unsigned short*)(ws);
  unsigned short* W1t = (unsigned short*)(ws + (8ull << 20));
  unsigned short* W2t = (unsigned short*)(ws + (16ull << 20));
  unsigned short* H   = (unsigned short*)(ws + (18ull << 20));
  float* E  = (float*)(ws + (20ull << 20));
  unsigned short* P = (unsigned short*)(ws + (24ull << 20));
  float* SP = (float*)(ws + (40ull << 20));

  dim3 blk(256);
  prep<<<dim3(2048 + 1280), blk, 0, stream>>>(sbj, obj, W1, W2, Abf, W1t, W2t);

  // GEMM1: K=4096, 128^2 tiles, split-K=8 (KSLICE=512), z = XCD, bf16 partials
  mfma_gemm<512><<<dim3(512), blk, 0, stream>>>(Abf, W1t, P, K1);
  combine1<<<dim3(512), blk, 0, stream>>>(P, b1, H);
  // GEMM2: full-K, direct E output (no partials)
  gemm2_full<<<dim3(256), blk, 0, stream>>>(H, W2t, b2, E);
  // scores: 16-row b-chunks -> (64,8) grid, 2 blocks/CU
  score_partial<<<dim3(64, 8), blk, 0, stream>>>(E, labs, SP);
  score_reduce<<<dim3(128), blk, 0, stream>>>(SP, scores);
}